// Round 7
// baseline (137.143 us; speedup 1.0000x reference)
//
#include <hip/hip_runtime.h>
#include <hip/hip_bf16.h>

typedef __attribute__((ext_vector_type(8))) __bf16 bf16x8;
typedef __attribute__((ext_vector_type(4))) __bf16 bf16x4;
typedef __attribute__((ext_vector_type(4))) float  f32x4;

#define MFMA16(a, b, c) __builtin_amdgcn_mfma_f32_16x16x32_bf16((a), (b), (c), 0, 0, 0)

// B=2, S=4096, D=256, P=R=64. Flattened rows g = b*4096 + n (8192 total).
static constexpr size_t OFF_WOT  = 0;                        // bf16 [256][256] ([n][k]) 128 KiB
static constexpr size_t OFF_VT   = 1u << 20;                 // bf16 [2][64][8][256][8] packed V, 4 MiB
static constexpr size_t OFF_L    = 6u << 20;                 // f32  [8192][64]  2 MiB
static constexpr size_t OFF_R    = 8u << 20;                 // f32  [8192][64]  2 MiB
static constexpr size_t OFF_PART = 10u << 20;                // bf16 [4][8192][256] 16 MiB
static constexpr size_t OFF_ZP   = 26u << 20;                // f32  [4][8192]   128 KiB

__device__ __forceinline__ float fast_exp2(float x) {
  float e;
  asm("v_exp_f32 %0, %1" : "=v"(e) : "v"(x));
  return e;
}

__device__ __forceinline__ bf16x8 cvt8(float4 a, float4 b) {
  bf16x8 o;
  o[0] = (__bf16)a.x; o[1] = (__bf16)a.y; o[2] = (__bf16)a.z; o[3] = (__bf16)a.w;
  o[4] = (__bf16)b.x; o[5] = (__bf16)b.y; o[6] = (__bf16)b.z; o[7] = (__bf16)b.w;
  return o;
}

// --------- projections: V packed [bat][chunk][m8][d][j] (bf16), l, r (fp32)
// grid (128, 6): x = 64-row block; y: 0..3 Wv d-tiles, 4 -> Wl, 5 -> Wr.
// Each block self-transposes its W tile (fp32 -> bf16 [n][k]) through LDS;
// ct>=4 blocks additionally transpose a 256-elem slice of Wo for k_outfix.
__global__ __launch_bounds__(256) void k_proj(const float* __restrict__ x,
                                              const float* __restrict__ Wv,
                                              const float* __restrict__ Wl,
                                              const float* __restrict__ Wr,
                                              const float* __restrict__ Wo,
                                              __bf16* __restrict__ Vt,
                                              float* __restrict__ lbuf,
                                              float* __restrict__ rbuf,
                                              __bf16* __restrict__ Wot) {
  __shared__ __align__(16) __bf16 wt[64 * 264];     // [n_local][k], stride 264 (2-way free)
  __shared__ __align__(16) __bf16 vs[8 * 64 * 8];   // [m8][d_local][j]
  const int t = threadIdx.x;
  const int lane = t & 63, wave = t >> 6;
  const int l16 = lane & 15, quad = lane >> 4;
  const int wr = wave >> 1, wc = wave & 1;
  const int rbk = blockIdx.x;
  const int ct  = blockIdx.y;
  const float* Wsrc;
  int wstride, colbase;
  if (ct < 4)       { Wsrc = Wv; wstride = 256; colbase = ct * 64; }
  else if (ct == 4) { Wsrc = Wl; wstride = 64;  colbase = 0; }
  else              { Wsrc = Wr; wstride = 64;  colbase = 0; }

  // side job: Wo transpose slice (256 blocks x 256 elems = full 256x256)
  if (ct >= 4) {
    const int j = ((ct - 4) * 128 + rbk) * 256 + t;
    const int k = j >> 8, n = j & 255;
    Wot[n * 256 + k] = (__bf16)Wo[j];
  }

  // transpose this block's W tile into LDS: wt[n][k] = W[k][colbase+n]
  {
    const int kr = t >> 4;            // 0..15
    const int n4 = (t & 15) * 4;
#pragma unroll
    for (int kk = 0; kk < 16; ++kk) {
      const int k = kk * 16 + kr;
      float4 v = *(const float4*)(Wsrc + (size_t)k * wstride + colbase + n4);
      wt[(n4 + 0) * 264 + k] = (__bf16)v.x;
      wt[(n4 + 1) * 264 + k] = (__bf16)v.y;
      wt[(n4 + 2) * 264 + k] = (__bf16)v.z;
      wt[(n4 + 3) * 264 + k] = (__bf16)v.w;
    }
  }
  __syncthreads();

  const int row0 = rbk * 64 + wr * 32;
  const int c0l  = wc * 32;           // local col within the 64-col tile
  f32x4 acc[2][2] = {};
  for (int kk = 0; kk < 256; kk += 32) {
    const int ko = kk + quad * 8;
    const float* xr0 = x + (size_t)(row0 + l16) * 256 + ko;
    const float* xr1 = x + (size_t)(row0 + 16 + l16) * 256 + ko;
    bf16x8 a0 = cvt8(*(const float4*)xr0, *(const float4*)(xr0 + 4));
    bf16x8 a1 = cvt8(*(const float4*)xr1, *(const float4*)(xr1 + 4));
    bf16x8 b0 = *(const bf16x8*)(wt + (c0l + l16) * 264 + ko);
    bf16x8 b1 = *(const bf16x8*)(wt + (c0l + 16 + l16) * 264 + ko);
    acc[0][0] = MFMA16(a0, b0, acc[0][0]);
    acc[0][1] = MFMA16(a0, b1, acc[0][1]);
    acc[1][0] = MFMA16(a1, b0, acc[1][0]);
    acc[1][1] = MFMA16(a1, b1, acc[1][1]);
  }
  if (ct < 4) {
#pragma unroll
    for (int mt = 0; mt < 2; ++mt)
#pragma unroll
      for (int nt = 0; nt < 2; ++nt) {
        const int m8 = wr * 4 + mt * 2 + (quad >> 1);
        const int d  = wc * 32 + nt * 16 + l16;          // local d within 64
        bf16x4 o;
        o.x = (__bf16)acc[mt][nt][0];
        o.y = (__bf16)acc[mt][nt][1];
        o.z = (__bf16)acc[mt][nt][2];
        o.w = (__bf16)acc[mt][nt][3];
        *(bf16x4*)(&vs[m8 * 512 + d * 8 + (quad & 1) * 4]) = o;
      }
    __syncthreads();
    const int m8 = t >> 5, s32 = t & 31;
    const int bat = rbk >> 6, mc = rbk & 63;
    bf16x8 a = *(const bf16x8*)(&vs[m8 * 512 + s32 * 16]);
    bf16x8 b = *(const bf16x8*)(&vs[m8 * 512 + s32 * 16 + 8]);
    __bf16* dst = Vt + (size_t)bat * 1048576 + (size_t)mc * 16384 +
                  m8 * 2048 + ct * 512 + s32 * 16;
    *(bf16x8*)dst       = a;
    *(bf16x8*)(dst + 8) = b;
  } else {
    float* dstb = (ct == 4) ? lbuf : rbuf;
#pragma unroll
    for (int mt = 0; mt < 2; ++mt)
#pragma unroll
      for (int nt = 0; nt < 2; ++nt) {
        const int col = c0l + nt * 16 + l16;
        const int gr  = rbk * 64 + wr * 32 + mt * 16 + quad * 4;
#pragma unroll
        for (int rr = 0; rr < 4; ++rr)
          dstb[(size_t)(gr + rr) * 64 + col] = acc[mt][nt][rr];
      }
  }
}

// ---------------- main attention GEMM: part_s = P_s @ V (unnormalized), Z_s
// grid (64, 4): TM=128, TN=256, split-K=4 (k-span 1024 = 16 chunks of 64).
// 512 threads = 8 waves: 2 row-waves (64 rows, mt=4) x 4 col-waves (64 cols, nt=4).
// Each ds_read_b128 feeds 4 MFMAs -> LDS pipe (1152 cyc/kc) < MFMA (1242 cyc/kc).
__global__ __launch_bounds__(512, 2) void k_attn(const float* __restrict__ lbuf,
                                                 const float* __restrict__ rbuf,
                                                 const __bf16* __restrict__ Vt,
                                                 __bf16* __restrict__ part,
                                                 float* __restrict__ zpart) {
  __shared__ __align__(16) char smem[74240];   // vt[2][32KB] + ls[128][17]f32; epi ctile aliases
  __bf16* vt0 = (__bf16*)smem;
  __bf16* vt1 = (__bf16*)(smem + 32768);
  float*  ls  = (float*)(smem + 65536);        // [128][17]
  const int t = threadIdx.x;                   // 0..511
  const int lane = t & 63, w = t >> 6;
  const int l16 = lane & 15, quad = lane >> 4;
  const int wr = w >> 2, wc = w & 3;           // 2 row-waves x 4 col-waves
  const int rb = blockIdx.x;                   // 0..63
  const int sp = blockIdx.y;                   // 0..3
  const int g0 = rb * 128;
  const int bat = rb >> 5;
  const __bf16* Vbase = Vt + (size_t)bat * 1048576;
  const int ck0 = sp * 16;

  // l tile: rows g0..+127, chunk-cols ck0..+15 (stride 17)
  {
    const int idx = t * 4;
    const int row = idx >> 4, c = idx & 15;
    f32x4 v = *(const f32x4*)(lbuf + (size_t)(g0 + row) * 64 + ck0 + c);
    ls[row * 17 + c + 0] = v[0];
    ls[row * 17 + c + 1] = v[1];
    ls[row * 17 + c + 2] = v[2];
    ls[row * 17 + c + 3] = v[3];
  }
  // r fragments pre-scaled by log2(e), 4 row-tiles per wave
  const float LOG2E = 1.44269504088896f;
  float rreg[4][16];
#pragma unroll
  for (int mt = 0; mt < 4; ++mt) {
    const float* rp = rbuf + (size_t)(g0 + wr * 64 + mt * 16 + l16) * 64;
    f32x4 a = *(const f32x4*)(rp + quad * 8);
    f32x4 b = *(const f32x4*)(rp + quad * 8 + 4);
    f32x4 c = *(const f32x4*)(rp + 32 + quad * 8);
    f32x4 d = *(const f32x4*)(rp + 32 + quad * 8 + 4);
#pragma unroll
    for (int j = 0; j < 4; ++j) {
      rreg[mt][j]      = a[j] * LOG2E;
      rreg[mt][4 + j]  = b[j] * LOG2E;
      rreg[mt][8 + j]  = c[j] * LOG2E;
      rreg[mt][12 + j] = d[j] * LOG2E;
    }
  }

  f32x4 acc[4][4] = {};
  float zacc[4] = {0.f, 0.f, 0.f, 0.f};
  bf16x8 stg[4];

  // stage chunk 0 into vt0 (32 KB: 512 threads x 4 x 16 B, linear)
  {
    const __bf16* src = Vbase + (size_t)ck0 * 16384;
#pragma unroll
    for (int i = 0; i < 4; ++i) stg[i] = *(const bf16x8*)(src + (size_t)(i * 512 + t) * 8);
#pragma unroll
    for (int i = 0; i < 4; ++i) *(bf16x8*)(vt0 + (i * 512 + t) * 8) = stg[i];
  }
  __syncthreads();

  for (int kc = 0; kc < 16; ++kc) {
    __bf16* cur = (kc & 1) ? vt1 : vt0;
    __bf16* nxt = (kc & 1) ? vt0 : vt1;
    if (kc < 15) {
      const __bf16* src = Vbase + (size_t)(ck0 + kc + 1) * 16384;
#pragma unroll
      for (int i = 0; i < 4; ++i) stg[i] = *(const bf16x8*)(src + (size_t)(i * 512 + t) * 8);
    }
    // A-fragments of P, registers only (one v_exp per element)
    bf16x8 af[4][2];
#pragma unroll
    for (int mt = 0; mt < 4; ++mt) {
      const float lv = ls[(wr * 64 + mt * 16 + l16) * 17 + kc];
#pragma unroll
      for (int kk = 0; kk < 2; ++kk)
#pragma unroll
        for (int j = 0; j < 8; ++j) {
          const float e = fast_exp2(lv * rreg[mt][kk * 8 + j]);
          zacc[mt] += e;
          af[mt][kk][j] = (__bf16)e;
        }
    }
    // MFMA phase: each B-read feeds 4 MFMAs (mt=4)
#pragma unroll
    for (int kk = 0; kk < 2; ++kk)
#pragma unroll
      for (int nt = 0; nt < 4; ++nt) {
        bf16x8 bv = *(const bf16x8*)(cur + (kk * 4 + quad) * 2048 +
                                     (wc * 64 + nt * 16 + l16) * 8);
        acc[0][nt] = MFMA16(af[0][kk], bv, acc[0][nt]);
        acc[1][nt] = MFMA16(af[1][kk], bv, acc[1][nt]);
        acc[2][nt] = MFMA16(af[2][kk], bv, acc[2][nt]);
        acc[3][nt] = MFMA16(af[3][kk], bv, acc[3][nt]);
      }
    if (kc < 15) {
#pragma unroll
      for (int i = 0; i < 4; ++i) *(bf16x8*)(nxt + (i * 512 + t) * 8) = stg[i];
    }
    __syncthreads();
  }

  // Z partials (full k-range per lane after quad reduction; col-wave 0 writes)
#pragma unroll
  for (int mt = 0; mt < 4; ++mt) {
    float z = zacc[mt];
    z += __shfl_xor(z, 16);
    z += __shfl_xor(z, 32);
    if (wc == 0 && quad == 0)
      zpart[(size_t)sp * 8192 + g0 + wr * 64 + mt * 16 + l16] = z;
  }

  // epilogue: stage C tile (128x256 bf16, stride 264), coalesced 16-B writes
  __bf16* ctile = (__bf16*)smem;
#pragma unroll
  for (int mt = 0; mt < 4; ++mt)
#pragma unroll
    for (int nt = 0; nt < 4; ++nt) {
      const int r0 = wr * 64 + mt * 16 + quad * 4;
      const int c  = wc * 64 + nt * 16 + l16;
#pragma unroll
      for (int rr = 0; rr < 4; ++rr)
        ctile[(r0 + rr) * 264 + c] = (__bf16)acc[mt][nt][rr];
    }
  __syncthreads();
  __bf16* pb = part + (size_t)sp * (8192 * 256);
#pragma unroll
  for (int p = 0; p < 8; ++p) {
    const int u = p * 512 + t;
    const int row = u >> 5, seg = u & 31;
    *(bf16x8*)(pb + (size_t)(g0 + row) * 256 + seg * 8) =
        *(const bf16x8*)(ctile + row * 264 + seg * 8);
  }
}

// ------- fused fixup + output GEMM: out = ((sum_s part[s]) / Z) @ Wo (fp32)
// grid (256): 32-row blocks. 4 waves 2x2 (16 rows x 128 cols each). No LDS.
__global__ __launch_bounds__(256) void k_outfix(const __bf16* __restrict__ part,
                                                const float* __restrict__ zpart,
                                                const __bf16* __restrict__ Wot,
                                                float* __restrict__ out) {
  const int t = threadIdx.x;
  const int lane = t & 63, w = t >> 6;
  const int l16 = lane & 15, quad = lane >> 4;
  const int wr = w >> 1, wc = w & 1;
  const int rb = blockIdx.x;
  const int arow = rb * 32 + wr * 16 + l16;
  float z = 0.f;
#pragma unroll
  for (int s = 0; s < 4; ++s) z += zpart[(size_t)s * 8192 + arow];
  const float iz = 1.0f / z;
  f32x4 acc[8] = {};
#pragma unroll 2
  for (int ks = 0; ks < 8; ++ks) {
    const int k0 = ks * 32 + quad * 8;
    float sum[8] = {};
#pragma unroll
    for (int s = 0; s < 4; ++s) {
      bf16x8 p = *(const bf16x8*)(part + (size_t)s * (8192 * 256) + (size_t)arow * 256 + k0);
#pragma unroll
      for (int j = 0; j < 8; ++j) sum[j] += (float)p[j];
    }
    bf16x8 afr;
#pragma unroll
    for (int j = 0; j < 8; ++j) afr[j] = (__bf16)(sum[j] * iz);
#pragma unroll
    for (int nt = 0; nt < 8; ++nt) {
      bf16x8 bv = *(const bf16x8*)(Wot + (size_t)(wc * 128 + nt * 16 + l16) * 256 + k0);
      acc[nt] = MFMA16(afr, bv, acc[nt]);
    }
  }
#pragma unroll
  for (int nt = 0; nt < 8; ++nt) {
    const int col = wc * 128 + nt * 16 + l16;
    const int r0  = rb * 32 + wr * 16 + quad * 4;
#pragma unroll
    for (int rr = 0; rr < 4; ++rr)
      out[(size_t)(r0 + rr) * 256 + col] = acc[nt][rr];
  }
}

extern "C" void kernel_launch(void* const* d_in, const int* in_sizes, int n_in,
                              void* d_out, int out_size, void* d_ws, size_t ws_size,
                              hipStream_t stream) {
  const float* x  = (const float*)d_in[0];
  const float* Wl = (const float*)d_in[1];
  const float* Wr = (const float*)d_in[2];
  const float* Wv = (const float*)d_in[3];
  const float* Wo = (const float*)d_in[4];
  char* ws = (char*)d_ws;
  __bf16* Wot = (__bf16*)(ws + OFF_WOT);
  __bf16* Vt  = (__bf16*)(ws + OFF_VT);
  float*  lb  = (float*)(ws + OFF_L);
  float*  rbf = (float*)(ws + OFF_R);
  __bf16* prt = (__bf16*)(ws + OFF_PART);
  float*  zp  = (float*)(ws + OFF_ZP);
  float*  out = (float*)d_out;

  k_proj<<<dim3(128, 6), 256, 0, stream>>>(x, Wv, Wl, Wr, Wo, Vt, lb, rbf, Wot);
  k_attn<<<dim3(64, 4), 512, 0, stream>>>(lb, rbf, Vt, prt, zp);
  k_outfix<<<256, 256, 0, stream>>>(prt, zp, Wot, out);
}